// Round 7
// baseline (96.160 us; speedup 1.0000x reference)
//
#include <hip/hip_runtime.h>
#include <stdint.h>

#define N_ANCH 67200
#define KCAP   1000
#define CONF_THR 0.7f
#define NMS_THR  0.4f

// score-bits histogram: scores in (0.7, 1.0] -> bits in (0x3F333333, 0x3F800000]
// span = 0x4CCCCD ulp; shift 10 -> 4917 live buckets, NBUCK = 4992 = 78*64.
#define BUCK_BASE 0x3F333333u
#define BUCK_SHIFT 10
#define NBUCK 4992
#define CAP2B 2048            // LDS filtered-candidate capacity (M2 ~ 1010)

// ---- workspace layout (bytes) ----
#define OFF_CTR   0           // int[0]=M (candidates), int[1]=V (valid slots)
#define OFF_HIST  64          // NBUCK*4 = 19968 -> 20032
#define OFF_LIST  20032       // N_ANCH*8 = 537600 -> 557632
#define OFF_SCORE 557632      // 1024*4  -> 561728
#define OFF_BOX   561728      // 1024*16 -> 578112 (16B aligned)
#define OFF_LM    578112      // 1024*40 -> 619072
#define OFF_SUP   619072      // 1000*16*8 = 128000 -> 747072 (~0.71 MB total)

__device__ inline unsigned long long shfl_xor_u64(unsigned long long v, int m) {
    unsigned int lo = (unsigned int)__shfl_xor((int)(v & 0xffffffffull), m, 64);
    unsigned int hi = (unsigned int)__shfl_xor((int)(v >> 32), m, 64);
    return ((unsigned long long)hi << 32) | lo;
}

// K0: zero counters + histogram (dedicated kernel; rocclr fill was 41us).
__global__ __launch_bounds__(1024) void k_zero(int* __restrict__ ctr,
                                               int* __restrict__ hist) {
    int tid = threadIdx.x;
    if (tid < 16) ctr[tid] = 0;
    for (int t = tid; t < NBUCK; t += 1024) hist[t] = 0;
}

// K1: softmax score, threshold, wave-aggregated compact to list + histogram.
// key = (score_bits<<32) | (0xFFFFFFFF - index): descending key order ==
// lax.top_k order (ties -> ascending index). List order is nondeterministic
// (atomic), but exact ranking downstream makes outputs deterministic.
__global__ void k_front(const float* __restrict__ conf,
                        unsigned long long* __restrict__ list,
                        int* __restrict__ hist,
                        int* __restrict__ ctr) {
    int i = blockIdx.x * blockDim.x + threadIdx.x;
    int lane = threadIdx.x & 63;
    bool pass = false;
    unsigned long long key = 0ull;
    int b = 0;
    if (i < N_ANCH) {
        float2 c = reinterpret_cast<const float2*>(conf)[i];
        float m  = fmaxf(c.x, c.y);
        float e0 = expf(c.x - m);
        float e1 = expf(c.y - m);
        float s  = e1 / (e0 + e1);
        if (s > CONF_THR) {
            pass = true;
            unsigned int sb = __float_as_uint(s);
            key = ((unsigned long long)sb << 32)
                | (unsigned int)(0xFFFFFFFFu - (unsigned int)i);
            b = min((int)((sb - BUCK_BASE) >> BUCK_SHIFT), NBUCK - 1);
        }
    }
    unsigned long long mask = __ballot(pass);
    if (mask) {
        int leader = (int)__builtin_ctzll(mask);
        int base = 0;
        if (lane == leader) base = atomicAdd(&ctr[0], (int)__popcll(mask));
        base = __shfl(base, leader, 64);
        if (pass) {
            int pos = base + (int)__popcll(mask & ((1ull << lane) - 1ull));
            list[pos] = key;
            atomicAdd(&hist[b], 1);
        }
    }
}

// K2 (single block): hist->LDS, findcut, filter list>=B into LDS (wave-agg
// LDS atomics), exact rank-by-count (unique keys), decode top-V into slots.
__global__ __launch_bounds__(1024) void k_back(
        const unsigned long long* __restrict__ list,
        const int* __restrict__ hist,
        const float* __restrict__ loc,
        const float* __restrict__ land,
        const float* __restrict__ priors,
        int* __restrict__ ctr,
        float* __restrict__ sel_score,
        float* __restrict__ sel_box,
        float* __restrict__ sel_lm) {
#pragma clang fp contract(off)
    __shared__ int shist[NBUCK];              // ~20 KB
    __shared__ unsigned long long sk[CAP2B];  // 16 KB
    __shared__ int scnt;
    __shared__ int sB;
    int tid = threadIdx.x;
    int lane = tid & 63;
    int M = min(ctr[0], N_ANCH);

    for (int t = tid; t < NBUCK; t += 1024) shist[t] = hist[t];
    if (tid == 0) scnt = 0;
    __syncthreads();

    // findcut (wave 0): largest B with suffix-count >= KCAP, else 0
    if (tid < 64) {
        int acc = 0, B = 0;
        bool found = false;
        for (int t = 0; t < NBUCK / 64 && !found; ++t) {
            int base = NBUCK - 64 * (t + 1);
            int c = shist[base + lane];
            int ssum = c;
#pragma unroll
            for (int off = 1; off < 64; off <<= 1)
                ssum += __shfl_xor(ssum, off, 64);
            if (acc + ssum >= KCAP) {
                for (int l = 63; l >= 0; --l) {
                    int cl = (int)__builtin_amdgcn_readlane((unsigned int)c, l);
                    if (acc + cl >= KCAP) { B = base + l; found = true; break; }
                    acc += cl;
                }
            } else {
                acc += ssum;
            }
        }
        if (lane == 0) sB = found ? B : 0;
    }
    __syncthreads();
    int B = sB;

    // filter list >= B into LDS; 4-way batched loads for ILP, wave-agg append
    for (int t0 = 0; t0 < M; t0 += 4096) {
        unsigned long long k0 = 0, k1 = 0, k2 = 0, k3 = 0;
        int i0 = t0 + tid;
        if (i0          < M) k0 = list[i0];
        if (i0 + 1024   < M) k1 = list[i0 + 1024];
        if (i0 + 2048   < M) k2 = list[i0 + 2048];
        if (i0 + 3072   < M) k3 = list[i0 + 3072];
#pragma unroll
        for (int q = 0; q < 4; ++q) {
            unsigned long long k = (q == 0) ? k0 : (q == 1) ? k1 : (q == 2) ? k2 : k3;
            bool keep = false;
            if (k) {
                unsigned int sb = (unsigned int)(k >> 32);
                int b = min((int)((sb - BUCK_BASE) >> BUCK_SHIFT), NBUCK - 1);
                keep = (b >= B);
            }
            unsigned long long mask = __ballot(keep);
            if (mask) {
                int leader = (int)__builtin_ctzll(mask);
                int base = 0;
                if (lane == leader) base = atomicAdd(&scnt, (int)__popcll(mask));
                base = __shfl(base, leader, 64);
                if (keep) {
                    int pos = base + (int)__popcll(mask & ((1ull << lane) - 1ull));
                    if (pos < CAP2B) sk[pos] = k;
                }
            }
        }
    }
    __syncthreads();
    int M2 = min(scnt, CAP2B);
    int V = min(M, KCAP);
    if (tid == 0) ctr[1] = V;

    // exact rank-by-count over LDS (broadcast reads); each thread covers
    // candidates tid and tid+1024.
    unsigned long long my0 = (tid < M2) ? sk[tid] : 0ull;
    unsigned long long my1 = (tid + 1024 < M2) ? sk[tid + 1024] : 0ull;
    int cnt0 = 0, cnt1 = 0;
    for (int j = 0; j < M2; ++j) {
        unsigned long long v = sk[j];
        cnt0 += (v > my0) ? 1 : 0;
        cnt1 += (v > my1) ? 1 : 0;
    }

#pragma unroll
    for (int h = 0; h < 2; ++h) {
        int idx = tid + h * 1024;
        unsigned long long key = h ? my1 : my0;
        int r = h ? cnt1 : cnt0;
        if (idx < M2 && r < KCAP) {
            unsigned int a = 0xFFFFFFFFu - (unsigned int)(key & 0xFFFFFFFFull);
            sel_score[r] = __uint_as_float((unsigned int)(key >> 32));
            float pcx = priors[a*4+0], pcy = priors[a*4+1];
            float pw  = priors[a*4+2], ph  = priors[a*4+3];
            float l0 = loc[a*4+0], l1 = loc[a*4+1], l2 = loc[a*4+2], l3 = loc[a*4+3];
            // replicate reference op order exactly:
            float cx = pcx + (l0 * 0.1f) * pw;
            float cy = pcy + (l1 * 0.1f) * ph;
            float w  = pw * expf(l2 * 0.2f);
            float h2 = ph * expf(l3 * 0.2f);
            float x1 = cx - w * 0.5f;
            float y1 = cy - h2 * 0.5f;
            sel_box[r*4+0] = x1 * 1280.0f;
            sel_box[r*4+1] = y1 * 1280.0f;
            sel_box[r*4+2] = (x1 + w) * 1280.0f;
            sel_box[r*4+3] = (y1 + h2) * 1280.0f;
#pragma unroll
            for (int q = 0; q < 5; ++q) {
                float lx = land[a*10 + 2*q + 0];
                float ly = land[a*10 + 2*q + 1];
                sel_lm[r*10 + 2*q + 0] = (pcx + (lx * 0.1f) * pw) * 1280.0f;
                sel_lm[r*10 + 2*q + 1] = (pcy + (ly * 0.1f) * ph) * 1280.0f;
            }
        }
    }
}

// K3: suppression bitmask rows. sup[i][g] bit l set iff j=g*64+l satisfies
// j>i, both valid, iou(b_i,b_j) > NMS_THR. Parallel across 1000 blocks.
__global__ void k_sup(const float* __restrict__ sel_box,
                      const int* __restrict__ ctr,
                      unsigned long long* __restrict__ sup) {
#pragma clang fp contract(off)
    int i = blockIdx.x;
    int V = min(ctr[1], KCAP);
    int lane = threadIdx.x; // 64 threads
    float ax1 = 0.f, ay1 = 0.f, ax2 = 0.f, ay2 = 0.f, aarea = 0.f;
    bool irow = (i < V);
    if (irow) {
        ax1 = sel_box[i*4+0]; ay1 = sel_box[i*4+1];
        ax2 = sel_box[i*4+2]; ay2 = sel_box[i*4+3];
        aarea = (ax2 - ax1) * (ay2 - ay1);
    }
    for (int g = 0; g < 16; ++g) {
        int j = g * 64 + lane;
        bool pred = false;
        if (irow && j < V && j > i) {
            float4 b = reinterpret_cast<const float4*>(sel_box)[j];
            float barea = (b.z - b.x) * (b.w - b.y);
            float ltx = fmaxf(ax1, b.x), lty = fmaxf(ay1, b.y);
            float rbx = fminf(ax2, b.z), rby = fminf(ay2, b.w);
            float wx = fmaxf(rbx - ltx, 0.0f);
            float wy = fmaxf(rby - lty, 0.0f);
            float inter = wx * wy;
            float iou = inter / (aarea + barea - inter + 1e-12f);
            pred = iou > NMS_THR;
        }
        unsigned long long mask = __ballot(pred);
        if (lane == 0) sup[i*16 + g] = mask;
    }
}

// K4: blocked greedy NMS scan, sparsity-aware (round-6 version, unchanged
// logic). NOTE: readlane/readfirstlane return int; widen through unsigned int.
__global__ __launch_bounds__(1024) void k_nms_scan(
        const unsigned long long* __restrict__ sup,
        const int* __restrict__ ctr,
        const float* __restrict__ sel_score,
        const float* __restrict__ sel_box,
        const float* __restrict__ sel_lm,
        float* __restrict__ out) {
    __shared__ unsigned long long sup_r[1024][16]; // [row][w ^ (row&15)]
    __shared__ unsigned long long mshare[16];
    __shared__ unsigned long long keep_final[16];
    int tid = threadIdx.x;
    int wave = tid >> 6, lane = tid & 63;
    int V = min(ctr[1], KCAP);

    for (int idx = tid; idx < KCAP * 16; idx += 1024) {
        int r = idx >> 4, w = idx & 15;
        sup_r[r][w ^ (r & 15)] = sup[idx];
    }
    if (tid < 24 * 16) { // zero rows 1000..1023
        int r = 1000 + (tid >> 4), w = tid & 15;
        sup_r[r][w ^ (r & 15)] = 0ull;
    }
    unsigned long long kw;
    {
        int lo = wave * 64;
        kw = (V >= lo + 64) ? ~0ull : (V <= lo ? 0ull : ((1ull << (V - lo)) - 1ull));
    }
    __syncthreads();

    for (int c = 0; c < 16; ++c) {
        if (wave == c) {
            unsigned long long drow = sup_r[c*64 + lane][c ^ (lane & 15)];
            unsigned int dlo = (unsigned int)drow;
            unsigned int dhi = (unsigned int)(drow >> 32);
            unsigned long long nz = __ballot(drow != 0ull);
            unsigned long long m = kw;
            unsigned long long todo = m & nz;
            while (todo) {
                int i = (int)__builtin_ctzll(todo);
                i = __builtin_amdgcn_readfirstlane(i);
                unsigned long long di =
                    (((unsigned long long)(unsigned int)__builtin_amdgcn_readlane(dhi, i)) << 32)
                  |  (unsigned long long)(unsigned int)__builtin_amdgcn_readlane(dlo, i);
                m &= ~di;            // di only holds j>i bits
                todo &= ~di;         // suppressed rows never processed
                todo &= todo - 1ull; // clear bit i
            }
            kw = m;
            if (lane == 0) mshare[c] = m;
        }
        __syncthreads();
        if (wave > c) {
            unsigned long long m = mshare[c];
            unsigned long long contrib = ((m >> lane) & 1ull)
                ? sup_r[c*64 + lane][wave ^ (lane & 15)] : 0ull;
            if (__ballot(contrib != 0ull) != 0ull) {
#pragma unroll
                for (int off = 1; off < 64; off <<= 1)
                    contrib |= shfl_xor_u64(contrib, off);
                kw &= ~contrib;
            }
        }
    }
    if (lane == 0) keep_final[wave] = kw;
    __syncthreads();

    // write outputs: boxes [0,4000), scores [4000,5000), landms [5000,15000)
    for (int s = tid; s < KCAP; s += 1024) {
        bool kept = ((keep_final[s >> 6] >> (s & 63)) & 1ull) != 0ull;
        float4 b = make_float4(0.f, 0.f, 0.f, 0.f);
        float sc = 0.f;
        if (kept) {
            b  = reinterpret_cast<const float4*>(sel_box)[s];
            sc = sel_score[s];
        }
        reinterpret_cast<float4*>(out)[s] = b;
        out[4000 + s] = sc;
#pragma unroll
        for (int q = 0; q < 10; ++q)
            out[5000 + s*10 + q] = kept ? sel_lm[s*10 + q] : 0.f;
    }
}

extern "C" void kernel_launch(void* const* d_in, const int* in_sizes, int n_in,
                              void* d_out, int out_size, void* d_ws, size_t ws_size,
                              hipStream_t stream) {
    const float* loc    = (const float*)d_in[0];
    const float* conf   = (const float*)d_in[1];
    const float* land   = (const float*)d_in[2];
    const float* priors = (const float*)d_in[3];
    float* out = (float*)d_out;
    char* ws = (char*)d_ws;

    int* ctr                     = (int*)(ws + OFF_CTR);
    int* hist                    = (int*)(ws + OFF_HIST);
    unsigned long long* list     = (unsigned long long*)(ws + OFF_LIST);
    float* sel_score             = (float*)(ws + OFF_SCORE);
    float* sel_box               = (float*)(ws + OFF_BOX);
    float* sel_lm                = (float*)(ws + OFF_LM);
    unsigned long long* sup      = (unsigned long long*)(ws + OFF_SUP);

    int nb = (N_ANCH + 255) / 256; // 263
    k_zero<<<1, 1024, 0, stream>>>(ctr, hist);
    k_front<<<nb, 256, 0, stream>>>(conf, list, hist, ctr);
    k_back<<<1, 1024, 0, stream>>>(list, hist, loc, land, priors, ctr,
                                   sel_score, sel_box, sel_lm);
    k_sup<<<KCAP, 64, 0, stream>>>(sel_box, ctr, sup);
    k_nms_scan<<<1, 1024, 0, stream>>>(sup, ctr, sel_score, sel_box, sel_lm, out);
}

// Round 8
// 65.037 us; speedup vs baseline: 1.4785x; 1.4785x over previous
//
#include <hip/hip_runtime.h>
#include <stdint.h>

#define N_ANCH 67200
#define KCAP   1000
#define CONF_THR 0.7f
#define NMS_THR  0.4f

// score-bits histogram: scores in (0.7, 1.0] -> bits in (0x3F333333, 0x3F800000]
// span = 0x4CCCCD ulp; shift 10 -> 4917 live buckets; NBUCK = 5120 = 1024*5
// so the suffix-scan maps 5 buckets per thread exactly.
#define BUCK_BASE 0x3F333333u
#define BUCK_SHIFT 10
#define NBUCK 5120
#define CAP2B 4096            // LDS bucket-sorted key capacity (kept ~ 1010)

// ---- workspace layout (bytes) ----
#define OFF_CTR   0           // int[0]=M (candidates), int[1]=V (valid slots)
#define OFF_HIST  64          // NBUCK*4 = 20480 -> 20544
#define OFF_LIST  20544       // N_ANCH*8 = 537600 -> 558144
#define OFF_SCORE 558144      // 1024*4  -> 562240
#define OFF_BOX   562240      // 1024*16 -> 578624 (16B aligned)
#define OFF_LM    578624      // 1024*40 -> 619584
#define OFF_SUP   619584      // 1000*16*8 = 128000 -> 747584 (~0.71 MB total)

__device__ inline unsigned long long shfl_xor_u64(unsigned long long v, int m) {
    unsigned int lo = (unsigned int)__shfl_xor((int)(v & 0xffffffffull), m, 64);
    unsigned int hi = (unsigned int)__shfl_xor((int)(v >> 32), m, 64);
    return ((unsigned long long)hi << 32) | lo;
}

// K0: zero counters + histogram (dedicated kernel; rocclr fill was 41us).
__global__ __launch_bounds__(1024) void k_zero(int* __restrict__ ctr,
                                               int* __restrict__ hist) {
    int tid = threadIdx.x;
    if (tid < 16) ctr[tid] = 0;
    for (int t = tid; t < NBUCK; t += 1024) hist[t] = 0;
}

// K1: softmax score, threshold, wave-aggregated compact to list + histogram.
// key = (score_bits<<32) | (0xFFFFFFFF - index): descending key order ==
// lax.top_k order (ties -> ascending index). List order is nondeterministic
// (atomic), but exact ranking downstream makes outputs deterministic.
__global__ void k_front(const float* __restrict__ conf,
                        unsigned long long* __restrict__ list,
                        int* __restrict__ hist,
                        int* __restrict__ ctr) {
    int i = blockIdx.x * blockDim.x + threadIdx.x;
    int lane = threadIdx.x & 63;
    bool pass = false;
    unsigned long long key = 0ull;
    int b = 0;
    if (i < N_ANCH) {
        float2 c = reinterpret_cast<const float2*>(conf)[i];
        float m  = fmaxf(c.x, c.y);
        float e0 = expf(c.x - m);
        float e1 = expf(c.y - m);
        float s  = e1 / (e0 + e1);
        if (s > CONF_THR) {
            pass = true;
            unsigned int sb = __float_as_uint(s);
            key = ((unsigned long long)sb << 32)
                | (unsigned int)(0xFFFFFFFFu - (unsigned int)i);
            b = min((int)((sb - BUCK_BASE) >> BUCK_SHIFT), NBUCK - 1);
        }
    }
    unsigned long long mask = __ballot(pass);
    if (mask) {
        int leader = (int)__builtin_ctzll(mask);
        int base = 0;
        if (lane == leader) base = atomicAdd(&ctr[0], (int)__popcll(mask));
        base = __shfl(base, leader, 64);
        if (pass) {
            int pos = base + (int)__popcll(mask & ((1ull << lane) - 1ull));
            list[pos] = key;
            atomicAdd(&hist[b], 1);
        }
    }
}

// K2 (single block): hist->LDS, findcut, suffix-scan (counting-sort bases),
// bucket-scatter kept keys into LDS, exact rank = segment_start + within-
// bucket count (~4 compares/key), decode top-V straight into slot order.
__global__ __launch_bounds__(1024) void k_back(
        const unsigned long long* __restrict__ list,
        const int* __restrict__ hist,
        const float* __restrict__ loc,
        const float* __restrict__ land,
        const float* __restrict__ priors,
        int* __restrict__ ctr,
        float* __restrict__ sel_score,
        float* __restrict__ sel_box,
        float* __restrict__ sel_lm) {
#pragma clang fp contract(off)
    __shared__ int shist[NBUCK];              // hist, then overwritten by sufx
    __shared__ int sfill[NBUCK];              // per-bucket fill counters
    __shared__ unsigned long long sk[CAP2B];  // bucket-sorted keys (descending segs)
    __shared__ int swsum[16];
    __shared__ int sB;
    int tid = threadIdx.x;
    int lane = tid & 63, wv = tid >> 6;
    int M = min(ctr[0], N_ANCH);

    for (int t = tid; t < NBUCK; t += 1024) { shist[t] = hist[t]; sfill[t] = 0; }
    __syncthreads();

    // findcut (wave 0): largest B with suffix-count >= KCAP, else 0
    if (tid < 64) {
        int acc = 0, B = 0;
        bool found = false;
        for (int t = 0; t < NBUCK / 64 && !found; ++t) {
            int base = NBUCK - 64 * (t + 1);
            int c = shist[base + lane];
            int ssum = c;
#pragma unroll
            for (int off = 1; off < 64; off <<= 1)
                ssum += __shfl_xor(ssum, off, 64);
            if (acc + ssum >= KCAP) {
                for (int l = 63; l >= 0; --l) {
                    int cl = (int)__builtin_amdgcn_readlane((unsigned int)c, l);
                    if (acc + cl >= KCAP) { B = base + l; found = true; break; }
                    acc += cl;
                }
            } else {
                acc += ssum;
            }
        }
        if (lane == 0) sB = found ? B : 0;
    }
    __syncthreads();
    int B = sB;

    // suffix-scan: shist[b] <- sufx[b] = #keys in buckets > b (= descending-
    // sort segment start of bucket b). Thread t owns reversed positions
    // t*5..t*5+4, i.e. buckets NBUCK-1-t*5 ... (each thread reads/writes only
    // its own 5 buckets, so no extra barrier needed around the writeback).
    {
        int c[5];
#pragma unroll
        for (int k = 0; k < 5; ++k)
            c[k] = shist[NBUCK - 1 - (tid * 5 + k)];
        int tsum = c[0] + c[1] + c[2] + c[3] + c[4];
        int inc = tsum;
#pragma unroll
        for (int off = 1; off < 64; off <<= 1) {
            int n = __shfl_up(inc, off, 64);
            if (lane >= off) inc += n;
        }
        if (lane == 63) swsum[wv] = inc;
        __syncthreads();
        if (tid < 16) {
            int v = swsum[tid];
            int s = v;
#pragma unroll
            for (int off = 1; off < 16; off <<= 1) {
                int n = __shfl_up(s, off, 64);
                if (tid >= off) s += n;
            }
            swsum[tid] = s - v;  // exclusive wave base
        }
        __syncthreads();
        int run = swsum[wv] + inc - tsum;  // exclusive prefix (reversed order)
#pragma unroll
        for (int k = 0; k < 5; ++k) {
            shist[NBUCK - 1 - (tid * 5 + k)] = run;
            run += c[k];
        }
    }
    __syncthreads();

    // bucket-scatter kept keys (b >= B) into sk; 4-way batched global loads
    for (int t0 = 0; t0 < M; t0 += 4096) {
        unsigned long long kv[4] = {0ull, 0ull, 0ull, 0ull};
        int i0 = t0 + tid;
#pragma unroll
        for (int q = 0; q < 4; ++q)
            if (i0 + q * 1024 < M) kv[q] = list[i0 + q * 1024];
#pragma unroll
        for (int q = 0; q < 4; ++q) {
            unsigned long long k = kv[q];
            if (k) {
                unsigned int sb = (unsigned int)(k >> 32);
                int b = min((int)((sb - BUCK_BASE) >> BUCK_SHIFT), NBUCK - 1);
                if (b >= B) {
                    int off = atomicAdd(&sfill[b], 1);
                    int slot = shist[b] + off;
                    if (slot < CAP2B) sk[slot] = k;
                }
            }
        }
    }
    __syncthreads();

    int S = min((B > 0) ? shist[B - 1] : M, CAP2B);  // total kept (clipped)
    int V = min(M, KCAP);
    if (tid == 0) ctr[1] = V;

    // exact rank + decode. rank = segment_start + #same-bucket keys > mine.
    for (int s = tid; s < S; s += 1024) {
        unsigned long long key = sk[s];
        unsigned int sb = (unsigned int)(key >> 32);
        int b = min((int)((sb - BUCK_BASE) >> BUCK_SHIFT), NBUCK - 1);
        int seg0 = shist[b];
        int segn = sfill[b];
        int within = 0;
        for (int t = 0; t < segn && seg0 + t < CAP2B; ++t)
            within += (sk[seg0 + t] > key) ? 1 : 0;
        int r = seg0 + within;
        if (r < KCAP) {
            unsigned int a = 0xFFFFFFFFu - (unsigned int)(key & 0xFFFFFFFFull);
            sel_score[r] = __uint_as_float(sb);
            float pcx = priors[a*4+0], pcy = priors[a*4+1];
            float pw  = priors[a*4+2], ph  = priors[a*4+3];
            float l0 = loc[a*4+0], l1 = loc[a*4+1], l2 = loc[a*4+2], l3 = loc[a*4+3];
            // replicate reference op order exactly:
            float cx = pcx + (l0 * 0.1f) * pw;
            float cy = pcy + (l1 * 0.1f) * ph;
            float w  = pw * expf(l2 * 0.2f);
            float h2 = ph * expf(l3 * 0.2f);
            float x1 = cx - w * 0.5f;
            float y1 = cy - h2 * 0.5f;
            sel_box[r*4+0] = x1 * 1280.0f;
            sel_box[r*4+1] = y1 * 1280.0f;
            sel_box[r*4+2] = (x1 + w) * 1280.0f;
            sel_box[r*4+3] = (y1 + h2) * 1280.0f;
#pragma unroll
            for (int q = 0; q < 5; ++q) {
                float lx = land[a*10 + 2*q + 0];
                float ly = land[a*10 + 2*q + 1];
                sel_lm[r*10 + 2*q + 0] = (pcx + (lx * 0.1f) * pw) * 1280.0f;
                sel_lm[r*10 + 2*q + 1] = (pcy + (ly * 0.1f) * ph) * 1280.0f;
            }
        }
    }
}

// K3: suppression bitmask rows. sup[i][g] bit l set iff j=g*64+l satisfies
// j>i, both valid, iou(b_i,b_j) > NMS_THR. Parallel across 1000 blocks.
__global__ void k_sup(const float* __restrict__ sel_box,
                      const int* __restrict__ ctr,
                      unsigned long long* __restrict__ sup) {
#pragma clang fp contract(off)
    int i = blockIdx.x;
    int V = min(ctr[1], KCAP);
    int lane = threadIdx.x; // 64 threads
    float ax1 = 0.f, ay1 = 0.f, ax2 = 0.f, ay2 = 0.f, aarea = 0.f;
    bool irow = (i < V);
    if (irow) {
        ax1 = sel_box[i*4+0]; ay1 = sel_box[i*4+1];
        ax2 = sel_box[i*4+2]; ay2 = sel_box[i*4+3];
        aarea = (ax2 - ax1) * (ay2 - ay1);
    }
    for (int g = 0; g < 16; ++g) {
        int j = g * 64 + lane;
        bool pred = false;
        if (irow && j < V && j > i) {
            float4 b = reinterpret_cast<const float4*>(sel_box)[j];
            float barea = (b.z - b.x) * (b.w - b.y);
            float ltx = fmaxf(ax1, b.x), lty = fmaxf(ay1, b.y);
            float rbx = fminf(ax2, b.z), rby = fminf(ay2, b.w);
            float wx = fmaxf(rbx - ltx, 0.0f);
            float wy = fmaxf(rby - lty, 0.0f);
            float inter = wx * wy;
            float iou = inter / (aarea + barea - inter + 1e-12f);
            pred = iou > NMS_THR;
        }
        unsigned long long mask = __ballot(pred);
        if (lane == 0) sup[i*16 + g] = mask;
    }
}

// K4: blocked greedy NMS scan, sparsity-aware. NOTE: readlane/readfirstlane
// return int; widen through unsigned int (round-2 sign-extension bug).
__global__ __launch_bounds__(1024) void k_nms_scan(
        const unsigned long long* __restrict__ sup,
        const int* __restrict__ ctr,
        const float* __restrict__ sel_score,
        const float* __restrict__ sel_box,
        const float* __restrict__ sel_lm,
        float* __restrict__ out) {
    __shared__ unsigned long long sup_r[1024][16]; // [row][w ^ (row&15)]
    __shared__ unsigned long long mshare[16];
    __shared__ unsigned long long keep_final[16];
    int tid = threadIdx.x;
    int wave = tid >> 6, lane = tid & 63;
    int V = min(ctr[1], KCAP);

    for (int idx = tid; idx < KCAP * 16; idx += 1024) {
        int r = idx >> 4, w = idx & 15;
        sup_r[r][w ^ (r & 15)] = sup[idx];
    }
    if (tid < 24 * 16) { // zero rows 1000..1023
        int r = 1000 + (tid >> 4), w = tid & 15;
        sup_r[r][w ^ (r & 15)] = 0ull;
    }
    unsigned long long kw;
    {
        int lo = wave * 64;
        kw = (V >= lo + 64) ? ~0ull : (V <= lo ? 0ull : ((1ull << (V - lo)) - 1ull));
    }
    __syncthreads();

    for (int c = 0; c < 16; ++c) {
        if (wave == c) {
            unsigned long long drow = sup_r[c*64 + lane][c ^ (lane & 15)];
            unsigned int dlo = (unsigned int)drow;
            unsigned int dhi = (unsigned int)(drow >> 32);
            unsigned long long nz = __ballot(drow != 0ull);
            unsigned long long m = kw;
            unsigned long long todo = m & nz;
            while (todo) {
                int i = (int)__builtin_ctzll(todo);
                i = __builtin_amdgcn_readfirstlane(i);
                unsigned long long di =
                    (((unsigned long long)(unsigned int)__builtin_amdgcn_readlane(dhi, i)) << 32)
                  |  (unsigned long long)(unsigned int)__builtin_amdgcn_readlane(dlo, i);
                m &= ~di;            // di only holds j>i bits
                todo &= ~di;         // suppressed rows never processed
                todo &= todo - 1ull; // clear bit i
            }
            kw = m;
            if (lane == 0) mshare[c] = m;
        }
        __syncthreads();
        if (wave > c) {
            unsigned long long m = mshare[c];
            unsigned long long contrib = ((m >> lane) & 1ull)
                ? sup_r[c*64 + lane][wave ^ (lane & 15)] : 0ull;
            if (__ballot(contrib != 0ull) != 0ull) {
#pragma unroll
                for (int off = 1; off < 64; off <<= 1)
                    contrib |= shfl_xor_u64(contrib, off);
                kw &= ~contrib;
            }
        }
    }
    if (lane == 0) keep_final[wave] = kw;
    __syncthreads();

    // write outputs: boxes [0,4000), scores [4000,5000), landms [5000,15000)
    for (int s = tid; s < KCAP; s += 1024) {
        bool kept = ((keep_final[s >> 6] >> (s & 63)) & 1ull) != 0ull;
        float4 b = make_float4(0.f, 0.f, 0.f, 0.f);
        float sc = 0.f;
        if (kept) {
            b  = reinterpret_cast<const float4*>(sel_box)[s];
            sc = sel_score[s];
        }
        reinterpret_cast<float4*>(out)[s] = b;
        out[4000 + s] = sc;
#pragma unroll
        for (int q = 0; q < 10; ++q)
            out[5000 + s*10 + q] = kept ? sel_lm[s*10 + q] : 0.f;
    }
}

extern "C" void kernel_launch(void* const* d_in, const int* in_sizes, int n_in,
                              void* d_out, int out_size, void* d_ws, size_t ws_size,
                              hipStream_t stream) {
    const float* loc    = (const float*)d_in[0];
    const float* conf   = (const float*)d_in[1];
    const float* land   = (const float*)d_in[2];
    const float* priors = (const float*)d_in[3];
    float* out = (float*)d_out;
    char* ws = (char*)d_ws;

    int* ctr                     = (int*)(ws + OFF_CTR);
    int* hist                    = (int*)(ws + OFF_HIST);
    unsigned long long* list     = (unsigned long long*)(ws + OFF_LIST);
    float* sel_score             = (float*)(ws + OFF_SCORE);
    float* sel_box               = (float*)(ws + OFF_BOX);
    float* sel_lm                = (float*)(ws + OFF_LM);
    unsigned long long* sup      = (unsigned long long*)(ws + OFF_SUP);

    int nb = (N_ANCH + 255) / 256; // 263
    k_zero<<<1, 1024, 0, stream>>>(ctr, hist);
    k_front<<<nb, 256, 0, stream>>>(conf, list, hist, ctr);
    k_back<<<1, 1024, 0, stream>>>(list, hist, loc, land, priors, ctr,
                                   sel_score, sel_box, sel_lm);
    k_sup<<<KCAP, 64, 0, stream>>>(sel_box, ctr, sup);
    k_nms_scan<<<1, 1024, 0, stream>>>(sup, ctr, sel_score, sel_box, sel_lm, out);
}